// Round 2
// baseline (497.995 us; speedup 1.0000x reference)
//
#include <hip/hip_runtime.h>
#include <cstddef>

#define LEAKY(x) ((x) > 0.f ? (x) : 0.2f*(x))

// ---------------------------------------------------------------------------
// Kernel A: per image n = b*64+t (2048 blocks, 512 threads)
//   conv1(2->32, 3x3 s2, SAME pad (0,1)) + leaky
//   conv2(32->64, 3x3 s2, SAME pad (0,1)) + leaky
//   GAP -> proj(64->128) -> scorer MLP -> score
// conv1 output staged in LDS in 4 chunks of 8 channels to bound LDS.
// ---------------------------------------------------------------------------
__global__ __launch_bounds__(512) void kConvGapProjScore(
    const float* __restrict__ texts, const float* __restrict__ styles,
    const float* __restrict__ c1w, const float* __restrict__ c1b,
    const float* __restrict__ c2w, const float* __restrict__ c2b,
    const float* __restrict__ pw,  const float* __restrict__ pb,
    const float* __restrict__ v1w, const float* __restrict__ v1b,
    const float* __restrict__ v2w, const float* __restrict__ v2b,
    const float* __restrict__ v3w, const float* __restrict__ v3b,
    float* __restrict__ feats, float* __restrict__ scores)
{
    __shared__ float s_in[2][65][68];   // input, zero-padded row/col 64
    __shared__ float s_x1[8][33][34];   // conv1 out chunk, zero-padded idx 32
    __shared__ float s_w2t[72][64];     // conv2 weights transposed [cil*9+kk][co]
    __shared__ float s_w1[32][18];
    __shared__ float s_b1[32];
    __shared__ float s_b2[64];
    __shared__ float s_gap[64];
    __shared__ float s_f[128];
    __shared__ float s_h[128];
    __shared__ float s_red[2];

    const int n   = blockIdx.x;
    const int tid = threadIdx.x;

    // zero LDS (pads must be 0; conv1 writes only [0..31][0..31] each chunk)
    for (int i = tid; i < 2*65*68; i += 512) (&s_in[0][0][0])[i] = 0.f;
    for (int i = tid; i < 8*33*34; i += 512) (&s_x1[0][0][0])[i] = 0.f;
    for (int i = tid; i < 576; i += 512) (&s_w1[0][0])[i] = c1w[i];   // FIX: was if(tid<576) with 512 threads
    if (tid < 32) s_b1[tid] = c1b[tid];
    if (tid >= 64 && tid < 128) s_b2[tid-64] = c2b[tid-64];
    __syncthreads();

    // stage the 2-channel input image
    {
        const float4* src0 = (const float4*)(texts  + (size_t)n*4096);
        const float4* src1 = (const float4*)(styles + (size_t)n*4096);
        for (int i = tid; i < 1024; i += 512) {
            int e = i << 2, y = e >> 6, x = e & 63;
            *(float4*)&s_in[0][y][x] = src0[i];
            *(float4*)&s_in[1][y][x] = src1[i];
        }
    }
    __syncthreads();

    const int og  = tid >> 6;            // 0..7: wave id = c_out group (conv2) / channel (conv1)
    const int pg  = tid & 63;
    const int px  = pg & 15, py0 = pg >> 4;   // conv2: 4 positions py0+4q, col px
    const int p0x = pg & 31, pyg = pg >> 5;   // conv1: col p0x, rows pyg*16+j

    float acc[4][8];                     // conv2 accumulators [q][k], c_out = og*8+k
    #pragma unroll
    for (int q = 0; q < 4; ++q)
        #pragma unroll
        for (int k = 0; k < 8; ++k) acc[q][k] = 0.f;

    for (int ch = 0; ch < 4; ++ch) {
        // stage conv2 weight chunk (transposed for b128 broadcast reads)
        for (int i = tid; i < 72*64; i += 512) {
            int co = i & 63, r = i >> 6;
            int cil = r / 9, kk = r - cil*9;
            s_w2t[r][co] = c2w[(co*32 + ch*8 + cil)*9 + kk];
        }
        // conv1 for this chunk: each wave computes one output channel plane
        {
            const int co1 = ch*8 + og;
            float w[18];
            #pragma unroll
            for (int i = 0; i < 18; ++i) w[i] = s_w1[co1][i];
            const float b1 = s_b1[co1];
            for (int j = 0; j < 16; ++j) {
                const int py = pyg*16 + j;
                float a = b1;
                #pragma unroll
                for (int ci = 0; ci < 2; ++ci)
                    #pragma unroll
                    for (int kh = 0; kh < 3; ++kh) {
                        const float* row = &s_in[ci][2*py+kh][2*p0x];
                        float2 r01 = *(const float2*)row;
                        float  r2  = row[2];
                        const float* wp = &w[ci*9 + kh*3];
                        a += wp[0]*r01.x + wp[1]*r01.y + wp[2]*r2;
                    }
                s_x1[og][py][p0x] = LEAKY(a);
            }
        }
        __syncthreads();
        // conv2 partial accumulation over this chunk's 8 input channels
        for (int cil = 0; cil < 8; ++cil) {
            #pragma unroll
            for (int kh = 0; kh < 3; ++kh)
                #pragma unroll
                for (int kw = 0; kw < 3; ++kw) {
                    const int r = cil*9 + kh*3 + kw;
                    float4 wa = *(const float4*)&s_w2t[r][og*8];
                    float4 wb = *(const float4*)&s_w2t[r][og*8+4];
                    float xv[4];
                    #pragma unroll
                    for (int q = 0; q < 4; ++q)
                        xv[q] = s_x1[cil][2*(py0+4*q)+kh][2*px+kw];
                    #pragma unroll
                    for (int q = 0; q < 4; ++q) {
                        acc[q][0] += wa.x*xv[q]; acc[q][1] += wa.y*xv[q];
                        acc[q][2] += wa.z*xv[q]; acc[q][3] += wa.w*xv[q];
                        acc[q][4] += wb.x*xv[q]; acc[q][5] += wb.y*xv[q];
                        acc[q][6] += wb.z*xv[q]; acc[q][7] += wb.w*xv[q];
                    }
                }
        }
        __syncthreads();
    }

    // bias + leaky + GAP; wave og owns c_out = og*8..og*8+7, covers all 256 positions
    #pragma unroll
    for (int k = 0; k < 8; ++k) {
        const float b2 = s_b2[og*8 + k];
        float s = 0.f;
        #pragma unroll
        for (int q = 0; q < 4; ++q) {
            float v = acc[q][k] + b2;
            s += LEAKY(v);
        }
        #pragma unroll
        for (int off = 32; off; off >>= 1) s += __shfl_xor(s, off);
        if (pg == 0) s_gap[og*8 + k] = s * (1.f/256.f);
    }
    __syncthreads();

    // proj: feats[n][j] = sum_m gap[m]*pw[m][j] + pb[j]
    if (tid < 128) {
        float a = pb[tid];
        #pragma unroll 8
        for (int m = 0; m < 64; ++m) a += s_gap[m]*pw[m*128 + tid];
        feats[(size_t)n*128 + tid] = a;
        s_f[tid] = a;
    }
    __syncthreads();
    // scorer layer 1
    if (tid < 128) {
        float a = v1b[tid];
        #pragma unroll 8
        for (int m = 0; m < 128; ++m) a += s_f[m]*v1w[m*128 + tid];
        s_h[tid] = LEAKY(a);
    }
    __syncthreads();
    // scorer layer 2 + elementwise product with v3
    if (tid < 128) {
        float a = v2b[tid];
        #pragma unroll 8
        for (int m = 0; m < 128; ++m) a += s_h[m]*v2w[m*128 + tid];
        a = LEAKY(a);
        s_f[tid] = a * v3w[tid];
    }
    __syncthreads();
    if (tid < 128) {
        float p = s_f[tid];
        #pragma unroll
        for (int off = 32; off; off >>= 1) p += __shfl_xor(p, off);
        if ((tid & 63) == 0) s_red[tid >> 6] = p;
    }
    __syncthreads();
    if (tid == 0) scores[n] = tanhf(s_red[0] + s_red[1] + v3b[0]);
}

// ---------------------------------------------------------------------------
// Kernel B: per-batch argmax (first-index tie-break, matches jnp.argmax)
//           + gather selected feats row into res
// ---------------------------------------------------------------------------
__global__ __launch_bounds__(128) void kArgGather(
    const float* __restrict__ scores, const float* __restrict__ feats,
    float* __restrict__ res)
{
    __shared__ int s_idx;
    const int b = blockIdx.x, tid = threadIdx.x;
    if (tid < 64) {
        float v = scores[b*64 + tid];
        int   i = tid;
        #pragma unroll
        for (int off = 32; off; off >>= 1) {
            float ov = __shfl_xor(v, off);
            int   oi = __shfl_xor(i, off);
            if (ov > v || (ov == v && oi < i)) { v = ov; i = oi; }
        }
        if (tid == 0) s_idx = i;
    }
    __syncthreads();
    const int idx = s_idx;
    res[b*128 + tid] = feats[((size_t)b*64 + idx)*128 + tid];
}

// ---------------------------------------------------------------------------
// Kernel C: decoder. grid = b*8 + ot so blocks sharing a d2 column slice land
// on the same XCD (bid%8 heuristic) -> d2 read ~once from HBM per XCD slice.
// h (512) recomputed per block (cheap) to avoid a kernel + ws round-trip.
// ---------------------------------------------------------------------------
__global__ __launch_bounds__(512) void kDecode(
    const float* __restrict__ res,
    const float* __restrict__ d1w, const float* __restrict__ d1b,
    const float* __restrict__ d2w, const float* __restrict__ d2b,
    float* __restrict__ out)
{
    __shared__ float s_res[128];
    __shared__ float s_h[512];
    const int bid = blockIdx.x;
    const int b = bid >> 3, ot = bid & 7;
    const int tid = threadIdx.x;

    if (tid < 128) s_res[tid] = res[b*128 + tid];
    __syncthreads();
    {
        float a = d1b[tid];
        #pragma unroll 8
        for (int m = 0; m < 128; ++m) a += s_res[m]*d1w[m*512 + tid];
        s_h[tid] = LEAKY(a);
    }
    __syncthreads();
    const int o = ot*512 + tid;
    float a = d2b[o];
    for (int k = 0; k < 512; k += 4) {
        float4 h4 = *(const float4*)&s_h[k];
        a += h4.x*d2w[(size_t)(k+0)*4096 + o];
        a += h4.y*d2w[(size_t)(k+1)*4096 + o];
        a += h4.z*d2w[(size_t)(k+2)*4096 + o];
        a += h4.w*d2w[(size_t)(k+3)*4096 + o];
    }
    out[(size_t)b*4096 + o] = tanhf(a);
}

// ---------------------------------------------------------------------------
extern "C" void kernel_launch(void* const* d_in, const int* in_sizes, int n_in,
                              void* d_out, int out_size, void* d_ws, size_t ws_size,
                              hipStream_t stream)
{
    const float* texts  = (const float*)d_in[0];
    const float* styles = (const float*)d_in[1];
    const float* c1w = (const float*)d_in[2];
    const float* c1b = (const float*)d_in[3];
    const float* c2w = (const float*)d_in[4];
    const float* c2b = (const float*)d_in[5];
    const float* pw  = (const float*)d_in[6];
    const float* pb  = (const float*)d_in[7];
    const float* v1w = (const float*)d_in[8];
    const float* v1b = (const float*)d_in[9];
    const float* v2w = (const float*)d_in[10];
    const float* v2b = (const float*)d_in[11];
    const float* v3w = (const float*)d_in[12];
    const float* v3b = (const float*)d_in[13];
    const float* d1w = (const float*)d_in[14];
    const float* d1b = (const float*)d_in[15];
    const float* d2w = (const float*)d_in[16];
    const float* d2b = (const float*)d_in[17];

    float* feats  = (float*)d_ws;                 // 32*64*128
    float* scores = feats + 32*64*128;            // 32*64
    float* res    = scores + 32*64;               // 32*128

    kConvGapProjScore<<<dim3(2048), dim3(512), 0, stream>>>(
        texts, styles, c1w, c1b, c2w, c2b, pw, pb,
        v1w, v1b, v2w, v2b, v3w, v3b, feats, scores);
    kArgGather<<<dim3(32), dim3(128), 0, stream>>>(scores, feats, res);
    kDecode<<<dim3(256), dim3(512), 0, stream>>>(res, d1w, d1b, d2w, d2b,
                                                 (float*)d_out);
}

// Round 4
// 232.956 us; speedup vs baseline: 2.1377x; 2.1377x over previous
//
#include <hip/hip_runtime.h>
#include <cstddef>
#include <cstdint>

#define LEAKY(x) ((x) > 0.f ? (x) : 0.2f*(x))

typedef _Float16 f16x8  __attribute__((ext_vector_type(8)));
typedef float    f32x16 __attribute__((ext_vector_type(16)));

// ws float-offsets
#define WS_FEATS   0            // 32*64*128 = 262144 floats
#define WS_SCORES  262144       // 2048
#define WS_RES     264192       // 4096
#define WS_W2      268288       // fp16: 2ch*2pl*64*152 = 38912 halfs (19456 float slots)
#define WS_W1P     287744       // 576 floats

// ---------------------------------------------------------------------------
// Pre-kernel: pack conv2 weights into fp16 hi/lo split, layout
// W2[chunk][plane][co][152] with k = tap*16 + ci_in_chunk (k>=144 zero pad).
// Row stride 152 halfs = 19 * 16B granules (odd) -> B-frag reads cover all 8
// LDS 16B slots. Also pack conv1 weights [grun][ci][kh][co8*3+kw] for
// wave-uniform broadcast loads (grun = global run 0..3, co = grun*8 + c).
// ---------------------------------------------------------------------------
__global__ void kPack(const float* __restrict__ c1w, const float* __restrict__ c2w,
                      float* __restrict__ ws)
{
    _Float16* W2 = (_Float16*)(ws + WS_W2);
    float* w1p = ws + WS_W1P;
    const int t = threadIdx.x;  // 256
    for (int i = t; i < 2*64*152; i += 256) {
        int k = i % 152, rest = i / 152;
        int co = rest & 63, c = rest >> 6;
        _Float16 h = (_Float16)0.f, lo = (_Float16)0.f;
        if (k < 144) {
            int tap = k >> 4, cil = k & 15;
            float wv = c2w[(co*32 + c*16 + cil)*9 + tap];
            h  = (_Float16)wv;
            lo = (_Float16)(wv - (float)h);
        }
        W2[((size_t)(c*2 + 0)*64 + co)*152 + k] = h;
        W2[((size_t)(c*2 + 1)*64 + co)*152 + k] = lo;
    }
    // w1p flat i = ((grun*2+ci)*3+kh)*24 + c*3 + kw, grun 0..3
    for (int i = t; i < 576; i += 256) {
        int kw = i % 3; int r = i / 3;
        int c = r & 7; r >>= 3;
        int kh = r % 3; r /= 3;
        int ci = r & 1; int grun = r >> 1;
        int co = grun*8 + c;
        w1p[i] = c1w[co*18 + ci*9 + kh*3 + kw];
    }
}

// ---------------------------------------------------------------------------
// Kernel A: per image n (2048 blocks x 512 thr = 8 waves)
//   conv1 fp32 VALU (reg-blocked 8 c_out) -> x1 NHWC fp16 hi/lo in LDS
//   conv2 implicit-GEMM via v_mfma_f32_32x32x16_f16, 2-term split (3 MFMA)
//   GAP -> proj -> scorer MLP -> score  (all fp32)
// x1 x-index swizzled x^((x>>1)&1) to spread LDS 16B granule slots.
// ---------------------------------------------------------------------------
__global__ __launch_bounds__(512) void kA(
    const float* __restrict__ texts, const float* __restrict__ styles,
    const float* __restrict__ c1b, const float* __restrict__ c2b,
    const float* __restrict__ pw,  const float* __restrict__ pb,
    const float* __restrict__ v1w, const float* __restrict__ v1b,
    const float* __restrict__ v2w, const float* __restrict__ v2b,
    const float* __restrict__ v3w, const float* __restrict__ v3b,
    const float* __restrict__ wsro,
    float* __restrict__ feats, float* __restrict__ scores)
{
    __shared__ float    s_in[2][65][68];        // 35,360 B
    __shared__ _Float16 s_x1[2][33*33*16];      // 69,696 B  (hi, lo)
    __shared__ _Float16 s_B[2][64*152];         // 38,912 B  (hi, lo), one ci-chunk
    __shared__ float    s_part[8][64];
    __shared__ float    s_gap[64], s_f[128], s_h[128], s_red[2];

    const int n = blockIdx.x, tid = threadIdx.x;
    const int w = tid >> 6, l = tid & 63;

    // zero x1 (rows/cols 32 are permanent zero pads)
    {
        uint32_t* z = (uint32_t*)&s_x1[0][0];
        for (int i = tid; i < 33*33*16; i += 512) z[i] = 0u;   // covers both planes (2*17424 halfs = 17424 u32)
    }
    // stage the 2-channel input (row 64 / col 64..67 zero pads)
    for (int i = tid; i < 65*68/2; i += 512) {
        ((float2*)&s_in[0][0][0])[i] = make_float2(0.f, 0.f);
        ((float2*)&s_in[1][0][0])[i] = make_float2(0.f, 0.f);
    }
    __syncthreads();
    {
        const float4* src0 = (const float4*)(texts  + (size_t)n*4096);
        const float4* src1 = (const float4*)(styles + (size_t)n*4096);
        for (int i = tid; i < 1024; i += 512) {
            int e = i << 2, y = e >> 6, x = e & 63;
            *(float4*)&s_in[0][y][x] = src0[i];
            *(float4*)&s_in[1][y][x] = src1[i];
        }
    }

    const _Float16* W2g = (const _Float16*)(wsro + WS_W2);

    f32x16 acc0, acc1;
    #pragma unroll
    for (int r = 0; r < 16; ++r) { acc0[r] = 0.f; acc1[r] = 0.f; }

    for (int ch = 0; ch < 2; ++ch) {
        // ---- stage B chunk (hi+lo contiguous) ----
        {
            const uint32_t* src = (const uint32_t*)(W2g + (size_t)ch*2*64*152);
            uint32_t* dst = (uint32_t*)&s_B[0][0];
            for (int i = tid; i < 64*152; i += 512) dst[i] = src[i];  // 2*64*152 halfs = 64*152 u32
        }
        __syncthreads();   // also covers s_in staging on first iter / conv2 reads on second

        // ---- conv1 for c_out in [ch*16, ch*16+16) ----
        {
            const int run  = w >> 2;                 // waves 0-3: run0, 4-7: run1 (wave-uniform)
            const int coB  = ch*16 + run*8;
            const int posb = (w & 3)*64 + l;         // 0..255
            float a[4][8];
            #pragma unroll
            for (int c = 0; c < 8; ++c) {
                float b1 = c1b[coB + c];
                #pragma unroll
                for (int p = 0; p < 4; ++p) a[p][c] = b1;
            }
            const float* w1pg = wsro + WS_W1P + (ch*2 + run)*144;   // FIX: global run index (was run*144)
            #pragma unroll
            for (int ci = 0; ci < 2; ++ci)
            #pragma unroll
            for (int kh = 0; kh < 3; ++kh) {
                const float* wrow = w1pg + (ci*3 + kh)*24;
                float wv[24];
                #pragma unroll
                for (int q = 0; q < 6; ++q)
                    *(float4*)&wv[q*4] = *(const float4*)&wrow[q*4];   // wave-uniform -> scalar
                #pragma unroll
                for (int p = 0; p < 4; ++p) {
                    const int pos = posb + p*256, py = pos >> 5, px = pos & 31;
                    float2 i01 = *(const float2*)&s_in[ci][2*py + kh][2*px];
                    float  i2  = s_in[ci][2*py + kh][2*px + 2];
                    #pragma unroll
                    for (int c = 0; c < 8; ++c)
                        a[p][c] += wv[c*3]*i01.x + wv[c*3+1]*i01.y + wv[c*3+2]*i2;
                }
            }
            // leaky -> fp16 hi/lo split -> packed b128 writes (swizzled x)
            #pragma unroll
            for (int p = 0; p < 4; ++p) {
                const int pos = posb + p*256, py = pos >> 5, px = pos & 31;
                const int xs = px ^ ((px >> 1) & 1);
                const int eo = (py*33 + xs)*16 + run*8;
                _Float16 hh[8], ll[8];
                #pragma unroll
                for (int c = 0; c < 8; ++c) {
                    float v = LEAKY(a[p][c]);
                    _Float16 h = (_Float16)v;
                    hh[c] = h;
                    ll[c] = (_Float16)(v - (float)h);
                }
                *(uint4*)&s_x1[0][eo] = *(uint4*)hh;
                *(uint4*)&s_x1[1][eo] = *(uint4*)ll;
            }
        }
        __syncthreads();

        // ---- conv2: implicit-GEMM MFMA, one tap per K-step ----
        {
            const int pos = w*32 + (l & 31);
            const int py = pos >> 4, px = pos & 15;
            const int hf = l >> 5;            // k-half: ci-run hf*8
            const int co = l & 31;
            #pragma unroll
            for (int tap = 0; tap < 9; ++tap) {
                const int kh = tap / 3, kw = tap % 3;
                const int xr = 2*px + kw;
                const int xs = xr ^ ((xr >> 1) & 1);
                const int ae = ((2*py + kh)*33 + xs)*16 + hf*8;
                f16x8 Ah = *(const f16x8*)&s_x1[0][ae];
                f16x8 Al = *(const f16x8*)&s_x1[1][ae];
                const int be0 = co*152 + tap*16 + hf*8;
                const int be1 = be0 + 32*152;
                f16x8 Bh0 = *(const f16x8*)&s_B[0][be0];
                f16x8 Bl0 = *(const f16x8*)&s_B[1][be0];
                f16x8 Bh1 = *(const f16x8*)&s_B[0][be1];
                f16x8 Bl1 = *(const f16x8*)&s_B[1][be1];
                acc0 = __builtin_amdgcn_mfma_f32_32x32x16_f16(Ah, Bh0, acc0, 0, 0, 0);
                acc0 = __builtin_amdgcn_mfma_f32_32x32x16_f16(Ah, Bl0, acc0, 0, 0, 0);
                acc0 = __builtin_amdgcn_mfma_f32_32x32x16_f16(Al, Bh0, acc0, 0, 0, 0);
                acc1 = __builtin_amdgcn_mfma_f32_32x32x16_f16(Ah, Bh1, acc1, 0, 0, 0);
                acc1 = __builtin_amdgcn_mfma_f32_32x32x16_f16(Ah, Bl1, acc1, 0, 0, 0);
                acc1 = __builtin_amdgcn_mfma_f32_32x32x16_f16(Al, Bh1, acc1, 0, 0, 0);
            }
        }
        __syncthreads();   // protect s_x1 / s_B rewrite next chunk
    }

    // ---- bias + leaky + GAP (C row-mapping agnostic: sum ALL acc regs) ----
    {
        const float b20 = c2b[l & 31], b21 = c2b[(l & 31) + 32];
        float sum0 = 0.f, sum1 = 0.f;
        #pragma unroll
        for (int r = 0; r < 16; ++r) {
            sum0 += LEAKY(acc0[r] + b20);
            sum1 += LEAKY(acc1[r] + b21);
        }
        sum0 += __shfl_xor(sum0, 32);
        sum1 += __shfl_xor(sum1, 32);
        if (l < 32) { s_part[w][l] = sum0; s_part[w][l + 32] = sum1; }
    }
    __syncthreads();
    if (tid < 64) {
        float s = 0.f;
        #pragma unroll
        for (int ww = 0; ww < 8; ++ww) s += s_part[ww][tid];
        s_gap[tid] = s * (1.f/256.f);
    }
    __syncthreads();

    // ---- proj + scorer (fp32, as before) ----
    if (tid < 128) {
        float a = pb[tid];
        #pragma unroll 8
        for (int m = 0; m < 64; ++m) a += s_gap[m]*pw[m*128 + tid];
        feats[(size_t)n*128 + tid] = a;
        s_f[tid] = a;
    }
    __syncthreads();
    if (tid < 128) {
        float a = v1b[tid];
        #pragma unroll 8
        for (int m = 0; m < 128; ++m) a += s_f[m]*v1w[m*128 + tid];
        s_h[tid] = LEAKY(a);
    }
    __syncthreads();
    if (tid < 128) {
        float a = v2b[tid];
        #pragma unroll 8
        for (int m = 0; m < 128; ++m) a += s_h[m]*v2w[m*128 + tid];
        a = LEAKY(a);
        s_f[tid] = a * v3w[tid];
    }
    __syncthreads();
    if (tid < 128) {
        float p = s_f[tid];
        #pragma unroll
        for (int off = 32; off; off >>= 1) p += __shfl_xor(p, off);
        if ((tid & 63) == 0) s_red[tid >> 6] = p;
    }
    __syncthreads();
    if (tid == 0) scores[n] = tanhf(s_red[0] + s_red[1] + v3b[0]);
}

// ---------------------------------------------------------------------------
// Kernel B: per-batch argmax (first-index tie-break) + gather feats row
// ---------------------------------------------------------------------------
__global__ __launch_bounds__(128) void kArgGather(
    const float* __restrict__ scores, const float* __restrict__ feats,
    float* __restrict__ res)
{
    __shared__ int s_idx;
    const int b = blockIdx.x, tid = threadIdx.x;
    if (tid < 64) {
        float v = scores[b*64 + tid];
        int   i = tid;
        #pragma unroll
        for (int off = 32; off; off >>= 1) {
            float ov = __shfl_xor(v, off);
            int   oi = __shfl_xor(i, off);
            if (ov > v || (ov == v && oi < i)) { v = ov; i = oi; }
        }
        if (tid == 0) s_idx = i;
    }
    __syncthreads();
    const int idx = s_idx;
    res[b*128 + tid] = feats[((size_t)b*64 + idx)*128 + tid];
}

// ---------------------------------------------------------------------------
// Kernel C: decoder (fp32). bid%8 -> same d2 column slice per XCD.
// ---------------------------------------------------------------------------
__global__ __launch_bounds__(512) void kDecode(
    const float* __restrict__ res,
    const float* __restrict__ d1w, const float* __restrict__ d1b,
    const float* __restrict__ d2w, const float* __restrict__ d2b,
    float* __restrict__ out)
{
    __shared__ float s_res[128];
    __shared__ float s_h[512];
    const int bid = blockIdx.x;
    const int b = bid >> 3, ot = bid & 7;
    const int tid = threadIdx.x;

    if (tid < 128) s_res[tid] = res[b*128 + tid];
    __syncthreads();
    {
        float a = d1b[tid];
        #pragma unroll 8
        for (int m = 0; m < 128; ++m) a += s_res[m]*d1w[m*512 + tid];
        s_h[tid] = LEAKY(a);
    }
    __syncthreads();
    const int o = ot*512 + tid;
    float a = d2b[o];
    for (int k = 0; k < 512; k += 4) {
        float4 h4 = *(const float4*)&s_h[k];
        a += h4.x*d2w[(size_t)(k+0)*4096 + o];
        a += h4.y*d2w[(size_t)(k+1)*4096 + o];
        a += h4.z*d2w[(size_t)(k+2)*4096 + o];
        a += h4.w*d2w[(size_t)(k+3)*4096 + o];
    }
    out[(size_t)b*4096 + o] = tanhf(a);
}

// ---------------------------------------------------------------------------
extern "C" void kernel_launch(void* const* d_in, const int* in_sizes, int n_in,
                              void* d_out, int out_size, void* d_ws, size_t ws_size,
                              hipStream_t stream)
{
    const float* texts  = (const float*)d_in[0];
    const float* styles = (const float*)d_in[1];
    const float* c1w = (const float*)d_in[2];
    const float* c1b = (const float*)d_in[3];
    const float* c2w = (const float*)d_in[4];
    const float* c2b = (const float*)d_in[5];
    const float* pw  = (const float*)d_in[6];
    const float* pb  = (const float*)d_in[7];
    const float* v1w = (const float*)d_in[8];
    const float* v1b = (const float*)d_in[9];
    const float* v2w = (const float*)d_in[10];
    const float* v2b = (const float*)d_in[11];
    const float* v3w = (const float*)d_in[12];
    const float* v3b = (const float*)d_in[13];
    const float* d1w = (const float*)d_in[14];
    const float* d1b = (const float*)d_in[15];
    const float* d2w = (const float*)d_in[16];
    const float* d2b = (const float*)d_in[17];

    float* ws     = (float*)d_ws;
    float* feats  = ws + WS_FEATS;
    float* scores = ws + WS_SCORES;
    float* res    = ws + WS_RES;

    kPack<<<dim3(1), dim3(256), 0, stream>>>(c1w, c2w, ws);
    kA<<<dim3(2048), dim3(512), 0, stream>>>(
        texts, styles, c1b, c2b, pw, pb,
        v1w, v1b, v2w, v2b, v3w, v3b,
        (const float*)ws, feats, scores);
    kArgGather<<<dim3(32), dim3(128), 0, stream>>>(scores, feats, res);
    kDecode<<<dim3(256), dim3(512), 0, stream>>>(res, d1w, d1b, d2w, d2b,
                                                 (float*)d_out);
}